// Round 1
// 163.312 us; speedup vs baseline: 1.0833x; 1.0833x over previous
//
#include <hip/hip_runtime.h>
#include <stdint.h>

#define N_ANCH 36864
#define KCAND  4096
#define NBUCK  384
#define NSEL   300
#define NGT    64
#define NBATCH 16
#define SCORE_THRESH 0.908f

typedef unsigned long long u64;

__device__ __forceinline__ float clip01(float v) { return fminf(fmaxf(v, 0.0f), 1.0f); }

// Exact decision "RN(inter/D) >= 0.5f" without division in the common case.
// D is computed in the reference's exact op order: ((aa+ab) - inter) + 1e-7f.
// Proof: q = RN(inter/D) >= 0.5  <=>  inter/D >= 0.5 - 2^-26 (tie rounds up to
// 0.5, which has an even mantissa).
//   hi:  inter >= 0.5*D (exact product)  =>  inter/D >= 0.5      => q >= 0.5.
//   lo:  r = RN(dt*(1-2^-23)) <= dt*(1-2^-24) < D*(0.5-2^-26);
//        inter < r  =>  inter/D < 0.5 - 2^-26  =>  q < 0.5.
// Band [r, dt): fall back to the actual IEEE division (prob ~2^-23 per pair).
__device__ __forceinline__ bool supp_half(const float4 A, const float aa,
                                          const float4 B, const float ab) {
    float y1 = fmaxf(A.x, B.x);
    float x1 = fmaxf(A.y, B.y);
    float y2 = fminf(A.z, B.z);
    float x2 = fminf(A.w, B.w);
    float ih = fmaxf(y2 - y1, 0.0f);
    float iw = fmaxf(x2 - x1, 0.0f);
    float inter = ih * iw;
    float D  = ((aa + ab) - inter) + 1e-7f;   // exact reference op order
    float dt = 0.5f * D;                      // exact (no subnormals: D >= 1e-7)
    float r  = fmaf(dt, -0x1p-23f, dt);
    bool hi  = inter >= dt;                   // definitely q >= 0.5
    bool unc = (!hi) && (inter >= r);         // boundary band -> divide
    if (__builtin_expect(__any((int)unc), 0))
        return (inter / D) >= 0.5f;           // exact for every lane
    return hi;
}

__device__ __forceinline__ float4 decode_one(const float4 a4, const float4 d4) {
    float ah = a4.z - a4.x, aw = a4.w - a4.y;
    float acy = a4.x + 0.5f * ah, acx = a4.y + 0.5f * aw;
    float h = expf(d4.z) * ah, w = expf(d4.w) * aw;
    float cy = d4.x * ah + acy, cx = d4.y * aw + acx;
    float y1 = cy - 0.5f * h, x1 = cx - 0.5f * w;
    return make_float4(y1, x1, y1 + h, x1 + w);
}

// scores in (0.908, 1.0) all share exponent 0x7E -> ulp-linear bucket digit,
// ascending digit == descending score. width 4096 ulps -> lambda ~9 per bucket.
__device__ __forceinline__ int bucket_of(float s) {
    unsigned d = (0x3F800000u - __float_as_uint(s)) >> 12;
    return (d < NBUCK) ? (int)d : (NBUCK - 1);
}

__global__ __launch_bounds__(1024)
void roi_bbox_kernel(const float* __restrict__ deltas,
                     const float* __restrict__ labels,
                     const float* __restrict__ anchors,
                     const float* __restrict__ gt,
                     float* __restrict__ out)
{
    __shared__ u64    s_sorted[KCAND];   // 32 KB, bucket-ordered then rank-sorted
    __shared__ int    s_hist[NBUCK];
    __shared__ int    s_cur[NBUCK];
    __shared__ int    s_base[NBUCK + 1];
    __shared__ float4 s_accB[NSEL];      // accepted raw (unclipped) boxes, pop order
    __shared__ float  s_accA[NSEL];      // accepted areas (computed once at accept)
    __shared__ float4 s_cbox[2][64];     // double-buffered chunk boxes
    __shared__ float  s_carea[2][64];    // double-buffered chunk areas
    __shared__ unsigned int s_pre[2][64];    // double-buffered suppression masks
    __shared__ unsigned int s_gmlo[2][64];
    __shared__ unsigned int s_gmhi[2][64];
    __shared__ int   s_accCount;
    __shared__ float s_merged[NSEL];
    __shared__ int   s_gtbest[NSEL];
    __shared__ float4 s_gt[NGT];
    __shared__ int   s_selidx[64];

    const int b    = blockIdx.x;
    const int tid  = threadIdx.x;
    const int lane = tid & 63;
    const int wv   = tid >> 6;
    const float*  sc    = labels + (size_t)b * N_ANCH;
    const float4* sc4   = (const float4*)sc;
    const float4* anch4 = (const float4*)(anchors + (size_t)b * N_ANCH * 4);
    const float4* del4  = (const float4*)(deltas  + (size_t)b * N_ANCH * 4);
    const float4* gt4   = (const float4*)(gt + (size_t)b * NGT * 4);

    if (tid < NBUCK) s_hist[tid] = 0;
    if (tid == 0) s_accCount = 0;
    __syncthreads();

    // ---- Phase A1: bucket histogram (float4-vectorized) ----
    for (int i = tid; i < N_ANCH / 4; i += 1024) {
        float4 v = sc4[i];
        float vv[4] = {v.x, v.y, v.z, v.w};
        #pragma unroll
        for (int k = 0; k < 4; ++k)
            if (vv[k] > SCORE_THRESH) atomicAdd(&s_hist[bucket_of(vv[k])], 1);
    }
    __syncthreads();

    // ---- exclusive scan of 384 counts (wave 0: 6 counts/lane + shfl scan) ----
    if (tid < 64) {
        int c[6]; int sum = 0;
        #pragma unroll
        for (int k = 0; k < 6; ++k) { c[k] = s_hist[tid * 6 + k]; sum += c[k]; }
        int inc = sum;
        #pragma unroll
        for (int off = 1; off < 64; off <<= 1) {
            int v = __shfl_up(inc, off);
            if (lane >= off) inc += v;
        }
        int excl = inc - sum;
        #pragma unroll
        for (int k = 0; k < 6; ++k) {
            s_base[tid * 6 + k] = excl;
            s_cur[tid * 6 + k]  = excl;
            excl += c[k];
        }
        if (tid == 63) s_base[NBUCK] = excl;
    }
    __syncthreads();

    // ---- Phase A2: scatter keys into bucket regions (L2-hot reload, vectorized) ----
    for (int i = tid; i < N_ANCH / 4; i += 1024) {
        float4 v = sc4[i];
        float vv[4] = {v.x, v.y, v.z, v.w};
        #pragma unroll
        for (int k = 0; k < 4; ++k) {
            float sval = vv[k];
            if (sval > SCORE_THRESH) {
                int idx = i * 4 + k;
                int pos = atomicAdd(&s_cur[bucket_of(sval)], 1);
                if (pos < KCAND)
                    s_sorted[pos] = ((u64)__float_as_uint(sval) << 32)
                                  | (u64)(0xFFFFFFFFu - (unsigned)idx);
            }
        }
    }
    __syncthreads();

    // ---- per-bucket rank sort (one wave per bucket, no barriers inside) ----
    for (int bk = wv; bk < NBUCK; bk += 16) {
        int lo = s_base[bk], hi = s_base[bk + 1];
        if (lo > KCAND) lo = KCAND;
        if (hi > KCAND) hi = KCAND;
        int n = hi - lo;
        if (n <= 1) continue;
        u64 mykey = (lane < n) ? s_sorted[lo + lane] : 0ull;
        int rank = 0;
        for (int j = 0; j < n; ++j) {          // broadcast reads, conflict-free
            u64 kj = s_sorted[lo + j];
            rank += (kj > mykey);
        }
        if (lane < n) s_sorted[lo + rank] = mykey;  // in-wave: reads precede write
    }
    __syncthreads();

    int M = s_base[NBUCK]; if (M > KCAND) M = KCAND;

    // decode chunk 0 (+areas), zero both mask-buffer sets
    if (tid < 64) {
        s_pre[0][tid] = 0u; s_gmlo[0][tid] = 0u; s_gmhi[0][tid] = 0u;
        s_pre[1][tid] = 0u; s_gmlo[1][tid] = 0u; s_gmhi[1][tid] = 0u;
        if (tid < M) {
            u64 key = s_sorted[tid];
            int idx = (int)(0xFFFFFFFFu - (unsigned)(key & 0xFFFFFFFFull));
            float4 bx = decode_one(anch4[idx], del4[idx]);
            s_cbox[0][tid]  = bx;
            s_carea[0][tid] = (bx.z - bx.x) * (bx.w - bx.y);
        }
    }
    __syncthreads();

    // ---- Phase B: greedy NMS over sorted candidates, 64-wide chunks ----
    int accCount = 0;
    for (int start = 0; start < M && accCount < NSEL; start += 64) {
        int C = M - start; if (C > 64) C = 64;
        int buf = (start >> 6) & 1;
        int c = tid & 63;

        if (wv == 1) {
            // zero next chunk's mask buffers (consumed only after resolve barrier)
            s_pre[buf ^ 1][c]  = 0u;
            s_gmlo[buf ^ 1][c] = 0u;
            s_gmhi[buf ^ 1][c] = 0u;
            int ni = start + 64 + c;           // prefetch-decode next chunk
            if (ni < M) {
                u64 key = s_sorted[ni];
                int idx = (int)(0xFFFFFFFFu - (unsigned)(key & 0xFFFFFFFFull));
                float4 bx = decode_one(anch4[idx], del4[idx]);
                s_cbox[buf ^ 1][c]  = bx;
                s_carea[buf ^ 1][c] = (bx.z - bx.x) * (bx.w - bx.y);
            }
        } else if (c < C) {
            int sidx = (wv == 0) ? 0 : (wv - 1);   // 15 slices: waves {0,2..15}
            float4 bc = s_cbox[buf][c];
            float  ba = s_carea[buf][c];
            bool supp = false;
            for (int a = sidx; a < accCount; a += 15)
                supp |= supp_half(s_accB[a], s_accA[a], bc, ba);
            if (supp) atomicOr(&s_pre[buf][c], 1u);
            unsigned int mlo = 0u, mhi = 0u;
            for (int j = sidx; j < c; j += 15) {
                if (supp_half(s_cbox[buf][j], s_carea[buf][j], bc, ba)) {
                    if (j < 32) mlo |= 1u << j; else mhi |= 1u << (j - 32);
                }
            }
            if (mlo) atomicOr(&s_gmlo[buf][c], mlo);
            if (mhi) atomicOr(&s_gmhi[buf][c], mhi);
        }
        __syncthreads();

        // wave-0 resolution: iterate only over alive lanes (each pick == accept)
        if (tid < 64) {
            u64 mymask = ((u64)s_gmhi[buf][tid] << 32) | (u64)s_gmlo[buf][tid];
            bool alive = (tid < C) && (s_pre[buf][tid] == 0u);
            u64 accbits = 0ull;
            u64 done = 0ull;
            int room = NSEL - accCount;
            int na = 0;
            while (na < room) {
                u64 am  = __ballot(alive);
                u64 rem = am & ~done;
                if (!rem) break;
                int l = __ffsll(rem) - 1;
                done = (2ull << l) - 1ull;
                accbits |= (1ull << l);
                ++na;
                if ((mymask >> l) & 1ull) alive = false;
            }
            if ((accbits >> tid) & 1ull) {
                int rank = __popcll(accbits & ((1ull << tid) - 1ull));
                float4 bx = s_cbox[buf][tid];
                s_accB[accCount + rank] = bx;
                s_accA[accCount + rank] = (bx.z - bx.x) * (bx.w - bx.y);
            }
            if (tid == 0) s_accCount = accCount + __popcll(accbits);
        }
        __syncthreads();
        accCount = s_accCount;
    }

    // ---- Phase C: select_rois ----
    if (tid < NGT) s_gt[tid] = gt4[tid];
    __syncthreads();

    if (tid < NSEL) {
        float4 bx;
        if (tid < accCount) {
            float4 r = s_accB[tid];
            bx = make_float4(clip01(r.x), clip01(r.y), clip01(r.z), clip01(r.w));
        } else bx = make_float4(0.f, 0.f, 0.f, 0.f);
        float aa = (bx.z - bx.x) * (bx.w - bx.y);
        float best = -1e38f; int bi = 0;
        for (int g = 0; g < NGT; ++g) {
            float4 gb = s_gt[g];
            float y1 = fmaxf(bx.x, gb.x);
            float x1 = fmaxf(bx.y, gb.y);
            float y2 = fminf(bx.z, gb.z);
            float x2 = fminf(bx.w, gb.w);
            float ih = fmaxf(y2 - y1, 0.0f);
            float iw = fmaxf(x2 - x1, 0.0f);
            float inter = ih * iw;
            float ab = (gb.z - gb.x) * (gb.w - gb.y);
            float iou = inter / (aa + ab - inter + 1e-7f);
            if (iou > best) { best = iou; bi = g; }   // first-occurrence argmax
        }
        s_merged[tid] = best;
        s_gtbest[tid] = bi;
    }
    __syncthreads();

    // stable top-64 via rank selection: rank = #{j: v_j > v_i || (v_j==v_i && j<i)}
    if (tid < NSEL) {
        float v = s_merged[tid];
        int rank = 0;
        for (int j = 0; j < NSEL; ++j) {
            float u = s_merged[j];
            rank += (u > v) || (u == v && j < tid);
        }
        if (rank < 64) s_selidx[rank] = tid;
    }
    __syncthreads();

    // ---- outputs ----
    float* outIdx = out + (size_t)NBATCH * 128 * 4;   // 8192 box floats first
    if (tid < 256) {
        int r = tid >> 2, cc = tid & 3;
        int i = s_selidx[r];
        float val = 0.0f;
        if (i < accCount) {
            const float* p = (const float*)&s_accB[i];
            val = clip01(p[cc]);
        }
        out[((size_t)b * 128 + r) * 4 + cc] = val;
    } else if (tid < 512) {
        int j = tid - 256;
        out[((size_t)b * 128 + 64) * 4 + j] = 0.0f;   // TOTAL_NEG zero boxes
    } else if (tid < 576) {
        int r = tid - 512;
        outIdx[b * 64 + r] = (float)s_gtbest[s_selidx[r]];
    }
}

extern "C" void kernel_launch(void* const* d_in, const int* in_sizes, int n_in,
                              void* d_out, int out_size, void* d_ws, size_t ws_size,
                              hipStream_t stream) {
    const float* deltas  = (const float*)d_in[0];
    const float* labels  = (const float*)d_in[1];
    const float* anchors = (const float*)d_in[2];
    const float* gt      = (const float*)d_in[3];
    float* out = (float*)d_out;
    roi_bbox_kernel<<<NBATCH, 1024, 0, stream>>>(deltas, labels, anchors, gt, out);
}